// Round 19
// baseline (670.816 us; speedup 1.0000x reference)
//
#include <hip/hip_runtime.h>
#include <hip/hip_bf16.h>
#include <math.h>

#define SEQ_LEN 1024
#define BATCH_N 8
#define DMODEL 256
#define DINNER 512
#define DSTATE 16
#define DTRANK 16
#define ROWS (BATCH_N * SEQ_LEN)   // 8192
#define NCHUNK 64
#define CHUNK (SEQ_LEN / NCHUNK)   // 16
#define BD 8                       // d-channels per block (scan)

typedef unsigned short u16;
typedef u16 u16x8 __attribute__((ext_vector_type(8)));
typedef short bf16x8 __attribute__((ext_vector_type(8)));
typedef float f32x4 __attribute__((ext_vector_type(4)));

__device__ __forceinline__ float siluf(float x) { return x / (1.f + expf(-x)); }
__device__ __forceinline__ float softplusf(float x) {
    return fmaxf(x, 0.f) + log1pf(expf(-fabsf(x)));
}
__device__ __forceinline__ u16 bf16_rne(float x) {
    unsigned u = __builtin_bit_cast(unsigned, x);
    return (u16)((u + 0x7FFFu + ((u >> 16) & 1u)) >> 16);
}
__device__ __forceinline__ void cvt_hl(float x, u16& h, u16& l) {
    unsigned u = __builtin_bit_cast(unsigned, x);
    unsigned hb = (u + 0x7FFFu + ((u >> 16) & 1u)) >> 16;
    h = (u16)hb;
    float hf = __builtin_bit_cast(float, hb << 16);
    l = bf16_rne(x - hf);
}
__device__ __forceinline__ float pair_f(u16 h, u16 l) {
    return __builtin_bit_cast(float, (unsigned)h << 16) +
           __builtin_bit_cast(float, (unsigned)l << 16);
}
// fragment-swizzled activation address: tensor [R rows][Kc cols] stored as
// [Kc/32][R][32]; elem (row,c) at ((c>>5)*R + row)*32 + (c&31)
__device__ __forceinline__ size_t swa(int R, int row, int c) {
    return ((size_t)(c >> 5) * R + row) * 32 + (c & 31);
}

// x fp32 [8192][64] -> swizzled bf16 hi/lo pairs
__global__ __launch_bounds__(256) void cvt_x_swz(
    const float* __restrict__ x, u16* __restrict__ dh, u16* __restrict__ dl)
{
    int i = blockIdx.x * 256 + threadIdx.x;   // < ROWS*64
    int row = i >> 6, c = i & 63;
    u16 h, l;
    cvt_hl(x[i], h, l);
    size_t sw = swa(ROWS, row, c);
    dh[sw] = h;
    dl[sw] = l;
}

// all 4 weight tensors -> fragment-swizzled single bf16 ([k/32][Npad][32])
// segments: Wp(256x64), W_in 4x(1024x256), W_x 4x(48->64 x 512), W_out 4x(256x512)
#define CWT (16384 + 4 * 262144 + 4 * 32768 + 4 * 131072)   // 1720320
__global__ __launch_bounds__(256) void cvt_w_swz(
    const float* __restrict__ Wp, const float* __restrict__ W_in,
    const float* __restrict__ W_x, const float* __restrict__ W_out,
    u16* __restrict__ Wpb, u16* __restrict__ Wib,
    u16* __restrict__ Wxb, u16* __restrict__ Wob)
{
    long i = (long)blockIdx.x * 256 + threadIdx.x;
    if (i >= CWT) return;
    if (i < 16384) {                       // Wp: N=256 K=64
        int n = (int)(i >> 6), k = (int)(i & 63);
        Wpb[((k >> 5) * 256 + n) * 32 + (k & 31)] = bf16_rne(Wp[n * 64 + k]);
        return;
    }
    i -= 16384;
    if (i < 4 * 262144) {                  // W_in: N=1024 K=256
        int l = (int)(i >> 18), r = (int)(i & 262143);
        int n = r >> 8, k = r & 255;
        Wib[l * 262144 + ((k >> 5) * 1024 + n) * 32 + (k & 31)] =
            bf16_rne(W_in[l * 262144 + n * 256 + k]);
        return;
    }
    i -= 4 * 262144;
    if (i < 4 * 32768) {                   // W_x: N=48 (pad 64) K=512
        int l = (int)(i >> 15), r = (int)(i & 32767);
        int n = r >> 9, k = r & 511;
        float v = (n < 48) ? W_x[l * 48 * 512 + n * 512 + k] : 0.f;
        Wxb[l * 32768 + ((k >> 5) * 64 + n) * 32 + (k & 31)] = bf16_rne(v);
        return;
    }
    i -= 4 * 32768;
    {                                      // W_out: N=256 K=512
        int l = (int)(i >> 17), r = (int)(i & 131071);
        int n = r >> 9, k = r & 511;
        Wob[l * 131072 + ((k >> 5) * 256 + n) * 32 + (k & 31)] =
            bf16_rne(W_out[l * 131072 + n * 512 + k]);
    }
}

// ---------------------------------------------------------------------------
// LDS-free MFMA GEMM on fragment-swizzled operands (round-11 measured-good).
// A = bf16 hi/lo pair (swizzled, R=M), B = single bf16 (swizzled, Npad rows).
// acc += Ah*B + Al*B. Block 64x64 = 4 waves 2x2; per wave-iter 6 coalesced
// u16x8 loads + 8 MFMAs. No barriers, no LDS.
// EPI 0: fp32 row-major C.  EPI 1: swizzled pair C.
// ---------------------------------------------------------------------------
template<int EPI>
__global__ __launch_bounds__(256) void gemm_sw(
    const u16* __restrict__ Ah, const u16* __restrict__ Al,
    const u16* __restrict__ B,
    const float* __restrict__ bias, float* __restrict__ C,
    u16* __restrict__ Ch, u16* __restrict__ Cl,
    int M, int N, int Npad, int K, int ldc)
{
    const int tid  = threadIdx.x;
    const int wave = tid >> 6, lane = tid & 63;
    const int bm   = blockIdx.y * 64, bn = blockIdx.x * 64;
    const int wm   = (wave >> 1) * 32, wn = (wave & 1) * 32;
    const int fr   = lane & 15, quad = lane >> 4;

    f32x4 acc[2][2];
#pragma unroll
    for (int i = 0; i < 2; i++)
#pragma unroll
        for (int j = 0; j < 2; j++) acc[i][j] = (f32x4){0.f, 0.f, 0.f, 0.f};

    const size_t a0 = (size_t)(bm + wm + fr) * 32 + quad * 8;
    const size_t a1 = a0 + 16 * 32;
    const size_t b0 = (size_t)(bn + wn + fr) * 32 + quad * 8;
    const size_t b1 = b0 + 16 * 32;
    const size_t astep = (size_t)M * 32;
    const size_t bstep = (size_t)Npad * 32;

    const u16* pah = Ah;
    const u16* pal = Al;
    const u16* pb  = B;
#pragma unroll 2
    for (int k0 = 0; k0 < K; k0 += 32) {
        bf16x8 ah0 = *(const bf16x8*)(pah + a0);
        bf16x8 ah1 = *(const bf16x8*)(pah + a1);
        bf16x8 al0 = *(const bf16x8*)(pal + a0);
        bf16x8 al1 = *(const bf16x8*)(pal + a1);
        bf16x8 bv0 = *(const bf16x8*)(pb + b0);
        bf16x8 bv1 = *(const bf16x8*)(pb + b1);
        acc[0][0] = __builtin_amdgcn_mfma_f32_16x16x32_bf16(ah0, bv0, acc[0][0], 0, 0, 0);
        acc[0][0] = __builtin_amdgcn_mfma_f32_16x16x32_bf16(al0, bv0, acc[0][0], 0, 0, 0);
        acc[0][1] = __builtin_amdgcn_mfma_f32_16x16x32_bf16(ah0, bv1, acc[0][1], 0, 0, 0);
        acc[0][1] = __builtin_amdgcn_mfma_f32_16x16x32_bf16(al0, bv1, acc[0][1], 0, 0, 0);
        acc[1][0] = __builtin_amdgcn_mfma_f32_16x16x32_bf16(ah1, bv0, acc[1][0], 0, 0, 0);
        acc[1][0] = __builtin_amdgcn_mfma_f32_16x16x32_bf16(al1, bv0, acc[1][0], 0, 0, 0);
        acc[1][1] = __builtin_amdgcn_mfma_f32_16x16x32_bf16(ah1, bv1, acc[1][1], 0, 0, 0);
        acc[1][1] = __builtin_amdgcn_mfma_f32_16x16x32_bf16(al1, bv1, acc[1][1], 0, 0, 0);
        pah += astep; pal += astep; pb += bstep;
    }

    // C/D layout (m89-verified): row = quad*4 + reg, col = fr within 16x16 frag
#pragma unroll
    for (int i = 0; i < 2; i++) {
        const int r0 = bm + wm + 16 * i + quad * 4;
#pragma unroll
        for (int reg = 0; reg < 4; reg++) {
            const int row = r0 + reg;
#pragma unroll
            for (int j = 0; j < 2; j++) {
                const int col = bn + wn + 16 * j + fr;
                if (col < N) {
                    float v = acc[i][j][reg];
                    if (bias) v += bias[col];
                    if (EPI == 0) {
                        C[(size_t)row * ldc + col] = v;
                    } else {
                        u16 h, l;
                        cvt_hl(v, h, l);
                        size_t sw = swa(M, row, col);
                        Ch[sw] = h;
                        Cl[sw] = l;
                    }
                }
            }
        }
    }
}

// ---------------------------------------------------------------------------
// Extra-wide variant: 64x256 block (4 waves 2x2, each 32x128 = 2x8 frags).
// 32 MFMAs per 12 loads; quarter the A re-reads of the 64x64 tile.
// fp32 row-major C only. N % 256 == 0 assumed (xz: N=1024).
// ---------------------------------------------------------------------------
__global__ __launch_bounds__(256) void gemm_sw256(
    const u16* __restrict__ Ah, const u16* __restrict__ Al,
    const u16* __restrict__ B, float* __restrict__ C,
    int M, int Npad, int K, int ldc)
{
    const int tid  = threadIdx.x;
    const int wave = tid >> 6, lane = tid & 63;
    const int bm   = blockIdx.y * 64, bn = blockIdx.x * 256;
    const int wm   = (wave >> 1) * 32, wn = (wave & 1) * 128;
    const int fr   = lane & 15, quad = lane >> 4;

    f32x4 acc[2][8];
#pragma unroll
    for (int i = 0; i < 2; i++)
#pragma unroll
        for (int j = 0; j < 8; j++) acc[i][j] = (f32x4){0.f, 0.f, 0.f, 0.f};

    const size_t a0 = (size_t)(bm + wm + fr) * 32 + quad * 8;
    const size_t a1 = a0 + 16 * 32;
    size_t bofs[8];
#pragma unroll
    for (int j = 0; j < 8; j++)
        bofs[j] = (size_t)(bn + wn + 16 * j + fr) * 32 + quad * 8;
    const size_t astep = (size_t)M * 32;
    const size_t bstep = (size_t)Npad * 32;

    const u16* pah = Ah;
    const u16* pal = Al;
    const u16* pb  = B;
    for (int k0 = 0; k0 < K; k0 += 32) {
        bf16x8 ah0 = *(const bf16x8*)(pah + a0);
        bf16x8 ah1 = *(const bf16x8*)(pah + a1);
        bf16x8 al0 = *(const bf16x8*)(pal + a0);
        bf16x8 al1 = *(const bf16x8*)(pal + a1);
        bf16x8 bv[8];
#pragma unroll
        for (int j = 0; j < 8; j++) bv[j] = *(const bf16x8*)(pb + bofs[j]);
#pragma unroll
        for (int j = 0; j < 8; j++) {
            acc[0][j] = __builtin_amdgcn_mfma_f32_16x16x32_bf16(ah0, bv[j], acc[0][j], 0, 0, 0);
            acc[0][j] = __builtin_amdgcn_mfma_f32_16x16x32_bf16(al0, bv[j], acc[0][j], 0, 0, 0);
            acc[1][j] = __builtin_amdgcn_mfma_f32_16x16x32_bf16(ah1, bv[j], acc[1][j], 0, 0, 0);
            acc[1][j] = __builtin_amdgcn_mfma_f32_16x16x32_bf16(al1, bv[j], acc[1][j], 0, 0, 0);
        }
        pah += astep; pal += astep; pb += bstep;
    }

#pragma unroll
    for (int i = 0; i < 2; i++) {
        const int r0 = bm + wm + 16 * i + quad * 4;
#pragma unroll
        for (int reg = 0; reg < 4; reg++) {
            float* crow = C + (size_t)(r0 + reg) * ldc;
#pragma unroll
            for (int j = 0; j < 8; j++)
                crow[bn + wn + 16 * j + fr] = acc[i][j][reg];
        }
    }
}

// causal depthwise conv (k=4) + bias + silu -> swizzled bf16 pair xc.
// xz (fp32): [ROWS][1024], xh = cols 0..511
__global__ __launch_bounds__(256) void conv_silu_k(
    const float* __restrict__ xz, const float* __restrict__ cw,
    const float* __restrict__ cb, u16* __restrict__ xch, u16* __restrict__ xcl)
{
    int idx = blockIdx.x * 256 + threadIdx.x;
    int d = idx & (DINNER - 1);
    int row = idx >> 9;
    int t = row & (SEQ_LEN - 1);
    float4 w = *(const float4*)(cw + d * 4);
    float acc = cb[d];
    const float* p = xz + (size_t)row * 1024 + d;
    if (t >= 3) acc = fmaf(p[-3 * 1024], w.x, acc);
    if (t >= 2) acc = fmaf(p[-2 * 1024], w.y, acc);
    if (t >= 1) acc = fmaf(p[-1 * 1024], w.z, acc);
    acc = fmaf(p[0], w.w, acc);
    float v = siluf(acc);
    u16 h, l;
    cvt_hl(v, h, l);
    size_t sw = swa(ROWS, row, d);
    xch[sw] = h;
    xcl[sw] = l;
}

// dt v2: block = 512 threads (one per d), loops 16 rows; W_dt row held in
// registers, dtr row loads are wave-uniform (scalar-cache broadcast).
#define DT_RPB 16
__global__ __launch_bounds__(512) void dt_k(
    const float* __restrict__ xdbl,  // [ROWS][48]
    const float* __restrict__ Wdt,   // [512][16]
    const float* __restrict__ bdt,   // [512]
    float* __restrict__ dt)          // [ROWS][512]
{
    const int d  = threadIdx.x;          // 0..511
    const int r0 = blockIdx.x * DT_RPB;  // grid = ROWS/DT_RPB = 512
    float wv[16];
#pragma unroll
    for (int i = 0; i < 16; i += 4) *(float4*)&wv[i] = *(const float4*)(Wdt + d * 16 + i);
    const float bb = bdt[d];
#pragma unroll 4
    for (int r = 0; r < DT_RPB; ++r) {
        const float* q = xdbl + (size_t)(r0 + r) * 48;
        float qv[16];
#pragma unroll
        for (int i = 0; i < 16; i += 4) *(float4*)&qv[i] = *(const float4*)(q + i);
        float dot = bb;
#pragma unroll
        for (int i = 0; i < 16; i++) dot = fmaf(qv[i], wv[i], dot);
        dt[(size_t)(r0 + r) * 512 + d] = softplusf(dot);
    }
}

// ---------------------------------------------------------------------------
// Chunked selective scan (r14-exact: best measured 53.0 us). One thread per
// (b, d, chunk), 16 states in registers; dt precomputed; no A->C reg cache
// (spills — r8/r17 both confirmed). Round-7 swizzle (b = blk & 7).
// y pair overwrites xc in place.
// ---------------------------------------------------------------------------
__global__ __launch_bounds__(512, 4) void scan_k(
    u16* __restrict__ xch,           // swizzled pair hi; in: xc, out: y
    u16* __restrict__ xcl,           // pair lo
    const float* __restrict__ dt,    // [ROWS][512] softplus'd
    const float* __restrict__ xdbl,  // [ROWS][48]  (B at +16, C at +32)
    const float* __restrict__ xz,    // [ROWS][1024]  z at +512
    const float* __restrict__ A_log, // [512][16]
    const float* __restrict__ Dp)    // [512]
{
    const int tid = threadIdx.x;
    const int dl  = tid & (BD - 1);      // 0..7
    const int ch  = tid >> 3;            // 0..63
    const int b   = blockIdx.x & 7;      // batch -> XCD partition
    const int dg  = blockIdx.x >> 3;     // 0..63
    const int d   = dg * BD + dl;

    __shared__ float ldsP[NCHUNK * BD * 16];   // 32 KB (reused as H0)
    __shared__ float ldsS[NCHUNK * BD * 16];   // 32 KB

    bool pow_ok = true;
#pragma unroll
    for (int n = 0; n < 16; n++) {
        float An = -expf(A_log[d * 16 + n]);
        pow_ok = pow_ok && (fabsf(An + (float)(n + 1)) <= 1e-3f * (float)(n + 1));
    }
    const int t0 = b * SEQ_LEN + ch * CHUNK;
    const int base = (ch * BD + dl) * 16;
    const size_t xcb = ((size_t)(d >> 5) * ROWS) * 32 + (d & 31);  // + row*32

    // ---- Phase A ----
    float S[16];
#pragma unroll
    for (int n = 0; n < 16; n++) S[n] = 0.f;
    float sdt = 0.f;
#pragma unroll 2
    for (int t = 0; t < CHUNK; ++t) {
        const size_t row = (size_t)(t0 + t);
        const float* xr = xdbl + row * 48;
        float Bv[16];
#pragma unroll
        for (int i = 0; i < 16; i += 4) *(float4*)&Bv[i] = *(const float4*)(xr + 16 + i);
        float xcv = pair_f(xch[xcb + row * 32], xcl[xcb + row * 32]);
        float dtv = dt[row * 512 + d];
        sdt += dtv;
        float u = dtv * xcv;
        float p[16];
        if (pow_ok) {
            float e1 = expf(-dtv);
            p[0] = e1;
#pragma unroll
            for (int n = 1; n < 8; n++) p[n] = p[n - 1] * e1;
            float e8 = p[7];
#pragma unroll
            for (int n = 8; n < 16; n++) p[n] = p[n - 8] * e8;
        } else {
#pragma unroll
            for (int n = 0; n < 16; n++)
                p[n] = exp2f(dtv * (-expf(A_log[d * 16 + n])) * 1.44269504f);
        }
#pragma unroll
        for (int n = 0; n < 16; n++) S[n] = fmaf(p[n], S[n], u * Bv[n]);
    }
    {
        float p[16];
        if (pow_ok) {
            float e1 = expf(-sdt);
            p[0] = e1;
#pragma unroll
            for (int n = 1; n < 8; n++) p[n] = p[n - 1] * e1;
            float e8 = p[7];
#pragma unroll
            for (int n = 8; n < 16; n++) p[n] = p[n - 8] * e8;
        } else {
#pragma unroll
            for (int n = 0; n < 16; n++)
                p[n] = exp2f(sdt * (-expf(A_log[d * 16 + n])) * 1.44269504f);
        }
#pragma unroll
        for (int i = 0; i < 16; i += 4) {
            *(float4*)&ldsP[base + i] = *(float4*)&p[i];
            *(float4*)&ldsS[base + i] = *(float4*)&S[i];
        }
    }
    __syncthreads();

    // ---- Phase B ----
    if (tid < BD * 16) {
        const int dd = tid >> 4;
        const int nn = tid & 15;
        float h = 0.f;
#pragma unroll 4
        for (int c = 0; c < NCHUNK; ++c) {
            const int idx = (c * BD + dd) * 16 + nn;
            float Pv = ldsP[idx];
            float Sv = ldsS[idx];
            ldsP[idx] = h;
            h = fmaf(Pv, h, Sv);
        }
    }
    __syncthreads();

    // ---- Phase C ----
    float h[16];
#pragma unroll
    for (int i = 0; i < 16; i += 4) *(float4*)&h[i] = *(float4*)&ldsP[base + i];
    const float Dd = Dp[d];
#pragma unroll 2
    for (int t = 0; t < CHUNK; ++t) {
        const size_t row = (size_t)(t0 + t);
        const float* xr = xdbl + row * 48;
        float Bv[16], Cv[16];
#pragma unroll
        for (int i = 0; i < 16; i += 4) *(float4*)&Bv[i] = *(const float4*)(xr + 16 + i);
#pragma unroll
        for (int i = 0; i < 16; i += 4) *(float4*)&Cv[i] = *(const float4*)(xr + 32 + i);
        float xcv = pair_f(xch[xcb + row * 32], xcl[xcb + row * 32]);
        float zv  = xz[row * 1024 + 512 + d];
        float dtv = dt[row * 512 + d];
        float u = dtv * xcv;
        float p[16];
        if (pow_ok) {
            float e1 = expf(-dtv);
            p[0] = e1;
#pragma unroll
            for (int n = 1; n < 8; n++) p[n] = p[n - 1] * e1;
            float e8 = p[7];
#pragma unroll
            for (int n = 8; n < 16; n++) p[n] = p[n - 8] * e8;
        } else {
#pragma unroll
            for (int n = 0; n < 16; n++)
                p[n] = exp2f(dtv * (-expf(A_log[d * 16 + n])) * 1.44269504f);
        }
        float y = 0.f;
#pragma unroll
        for (int n = 0; n < 16; n++) {
            h[n] = fmaf(p[n], h[n], u * Bv[n]);
            y = fmaf(h[n], Cv[n], y);
        }
        y = fmaf(Dd, xcv, y);
        y *= siluf(zv);
        u16 yh, yl;
        cvt_hl(y, yh, yl);
        xch[xcb + row * 32] = yh;
        xcl[xcb + row * 32] = yl;
    }
}

// LayerNorm over 256 features -> swizzled bf16 pair output; 4 rows per block.
__global__ __launch_bounds__(256) void ln_k(
    const float* __restrict__ X, const float* __restrict__ g,
    const float* __restrict__ b2, u16* __restrict__ Yh, u16* __restrict__ Yl)
{
    int lane = threadIdx.x & 63;
    int row = blockIdx.x * 4 + (threadIdx.x >> 6);
    const float4 v = *(const float4*)(X + (size_t)row * 256 + lane * 4);
    float s = v.x + v.y + v.z + v.w;
    float q = v.x * v.x + v.y * v.y + v.z * v.z + v.w * v.w;
#pragma unroll
    for (int o = 1; o < 64; o <<= 1) { s += __shfl_xor(s, o, 64); q += __shfl_xor(q, o, 64); }
    float mean = s * (1.f / 256.f);
    float var = q * (1.f / 256.f) - mean * mean;
    float inv = rsqrtf(var + 1e-5f);
    float4 gg = *(const float4*)(g + lane * 4);
    float4 bb = *(const float4*)(b2 + lane * 4);
    float o0 = (v.x - mean) * inv * gg.x + bb.x;
    float o1 = (v.y - mean) * inv * gg.y + bb.y;
    float o2 = (v.z - mean) * inv * gg.z + bb.z;
    float o3 = (v.w - mean) * inv * gg.w + bb.w;
    ushort4 h4, l4;
    cvt_hl(o0, h4.x, l4.x); cvt_hl(o1, h4.y, l4.y);
    cvt_hl(o2, h4.z, l4.z); cvt_hl(o3, h4.w, l4.w);
    size_t sw = swa(ROWS, row, lane * 4);
    *(ushort4*)(Yh + sw) = h4;
    *(ushort4*)(Yl + sw) = l4;
}

// final stage 1: per (b, t-chunk of 16) partial dot with Wf -> part[512]
__global__ __launch_bounds__(256) void final1_k(
    const u16* __restrict__ Hh, const u16* __restrict__ Hl,
    const float* __restrict__ Wf, float* __restrict__ part)
{
    const int b   = blockIdx.x >> 6;     // 0..7
    const int ckt = blockIdx.x & 63;     // 0..63
    const int c   = threadIdx.x;
    const size_t cb = ((size_t)(c >> 5) * ROWS) * 32 + (c & 31);
    const int tbase = b * SEQ_LEN + ckt * 16;
    float s = 0.f;
#pragma unroll 4
    for (int t = 0; t < 16; t++) {
        size_t sw = cb + (size_t)(tbase + t) * 32;
        s += pair_f(Hh[sw], Hl[sw]);
    }
    float v = s * Wf[c];
    int lane = c & 63;
#pragma unroll
    for (int o = 1; o < 64; o <<= 1) v += __shfl_xor(v, o, 64);
    __shared__ float red[4];
    if (lane == 0) red[c >> 6] = v;
    __syncthreads();
    if (c == 0) part[blockIdx.x] = red[0] + red[1] + red[2] + red[3];
}

// final stage 2: combine 64 partials per batch
__global__ __launch_bounds__(512) void final2_k(
    const float* __restrict__ part, const float* __restrict__ bf,
    float* __restrict__ out)
{
    int tid = threadIdx.x;            // 512
    int b = tid >> 6, i = tid & 63;
    float v = part[b * 64 + i];
#pragma unroll
    for (int o = 1; o < 64; o <<= 1) v += __shfl_xor(v, o, 64);
    if (i == 0) out[b] = v * (1.f / 1024.f) + bf[0];
}

extern "C" void kernel_launch(void* const* d_in, const int* in_sizes, int n_in,
                              void* d_out, int out_size, void* d_ws, size_t ws_size,
                              hipStream_t stream)
{
    const float* x      = (const float*)d_in[0];
    const float* Wp     = (const float*)d_in[1];
    const float* bp     = (const float*)d_in[2];
    const float* W_in   = (const float*)d_in[3];
    const float* conv_w = (const float*)d_in[4];
    const float* conv_b = (const float*)d_in[5];
    const float* W_x    = (const float*)d_in[6];
    const float* W_dt   = (const float*)d_in[7];
    const float* b_dt   = (const float*)d_in[8];
    const float* A_log  = (const float*)d_in[9];
    const float* Dp     = (const float*)d_in[10];
    const float* W_out  = (const float*)d_in[11];
    const float* ln_g   = (const float*)d_in[12];
    const float* ln_b   = (const float*)d_in[13];
    const float* Wf     = (const float*)d_in[14];
    const float* bf     = (const float*)d_in[15];

    // ---- workspace layout ----
    char* w = (char*)d_ws;
    float* bufXZ = (float*)w;            w += (size_t)ROWS * 1024 * 4;  // 33.55 MB
    float* bufDT = (float*)w;            w += (size_t)ROWS * 512 * 4;   // 16.78 MB
    float* bufXD = (float*)w;            w += (size_t)ROWS * 48 * 4;    // 1.57 MB
    u16* xch  = (u16*)w;                 w += (size_t)ROWS * 512 * 2;
    u16* xcl  = (u16*)w;                 w += (size_t)ROWS * 512 * 2;
    u16* hh   = (u16*)w;                 w += (size_t)ROWS * 256 * 2;
    u16* hl   = (u16*)w;                 w += (size_t)ROWS * 256 * 2;
    u16* xih  = (u16*)w;                 w += (size_t)ROWS * 64 * 2;
    u16* xil  = (u16*)w;                 w += (size_t)ROWS * 64 * 2;
    u16* Wpb  = (u16*)w;                 w += (size_t)256 * 64 * 2;
    u16* Wib  = (u16*)w;                 w += (size_t)4 * 1024 * 256 * 2;
    u16* Wxb  = (u16*)w;                 w += (size_t)4 * 64 * 512 * 2;   // padded
    u16* Wob  = (u16*)w;                 w += (size_t)4 * 256 * 512 * 2;
    float* part = (float*)w;             w += 512 * 4;
    float* bufO = bufXZ;   // [ROWS][256] overlays bufXZ (dead after scan)

    dim3 blk(256);

    // one-time conversions (swizzled)
    cvt_x_swz<<<dim3(ROWS * 64 / 256), blk, 0, stream>>>(x, xih, xil);
    cvt_w_swz<<<dim3((CWT + 255) / 256), blk, 0, stream>>>(
        Wp, W_in, W_x, W_out, Wpb, Wib, Wxb, Wob);

    // h = x @ Wp^T + bp  (M=8192, N=Npad=256, K=64) -> swizzled pair
    gemm_sw<1><<<dim3(4, 128), blk, 0, stream>>>(xih, xil, Wpb, bp,
                                                 nullptr, hh, hl,
                                                 ROWS, DMODEL, DMODEL, 64, 0);

    for (int l = 0; l < 4; ++l) {
        const u16* Wil = Wib + (size_t)l * 1024 * 256;
        const u16* Wxl = Wxb + (size_t)l * 64 * 512;
        const u16* Wol = Wob + (size_t)l * 256 * 512;
        const float* cw  = conv_w + (size_t)l * DINNER * 4;
        const float* cb  = conv_b + (size_t)l * DINNER;
        const float* Wdt = W_dt   + (size_t)l * DINNER * DTRANK;
        const float* bdt = b_dt   + (size_t)l * DINNER;
        const float* Al  = A_log  + (size_t)l * DINNER * DSTATE;
        const float* Dl  = Dp     + (size_t)l * DINNER;
        const float* lg  = ln_g   + (size_t)l * DMODEL;
        const float* lb  = ln_b   + (size_t)l * DMODEL;

        // xz = h @ W_in^T  (N=Npad=1024, K=256) -> fp32, extra-wide 64x256
        gemm_sw256<<<dim3(4, 128), blk, 0, stream>>>(hh, hl, Wil, bufXZ,
                                                     ROWS, 1024, DMODEL, 1024);
        // conv + silu -> xc swizzled pairs
        conv_silu_k<<<dim3(ROWS * DINNER / 256), blk, 0, stream>>>(bufXZ, cw, cb, xch, xcl);
        // x_dbl = xc @ W_x^T  (N=48, Npad=64, K=512) -> fp32 row-major
        gemm_sw<0><<<dim3(1, 128), blk, 0, stream>>>(xch, xcl, Wxl, nullptr,
                                                     bufXD, nullptr, nullptr,
                                                     ROWS, 48, 64, DINNER, 48);
        // dt = softplus(dtr @ W_dt^T + b_dt)  (rank-16, register-resident W_dt)
        dt_k<<<dim3(ROWS / DT_RPB), dim3(512), 0, stream>>>(bufXD, Wdt, bdt, bufDT);
        // chunked selective scan (r14-exact) -> y pairs overwrite xc
        scan_k<<<dim3(512), dim3(512), 0, stream>>>(xch, xcl, bufDT, bufXD, bufXZ, Al, Dl);
        // out = y @ W_out^T  (N=Npad=256, K=512) -> fp32 bufO
        gemm_sw<0><<<dim3(4, 128), blk, 0, stream>>>(xch, xcl, Wol, nullptr,
                                                     bufO, nullptr, nullptr,
                                                     ROWS, DMODEL, DMODEL, DINNER, DMODEL);
        // layernorm -> h swizzled pairs
        ln_k<<<dim3(ROWS / 4), blk, 0, stream>>>(bufO, lg, lb, hh, hl);
    }

    final1_k<<<dim3(512), blk, 0, stream>>>(hh, hl, Wf, part);
    final2_k<<<dim3(1), dim3(512), 0, stream>>>(part, bf, (float*)d_out);

    (void)in_sizes; (void)n_in; (void)out_size; (void)ws_size;
}

// Round 20
// 664.752 us; speedup vs baseline: 1.0091x; 1.0091x over previous
//
#include <hip/hip_runtime.h>
#include <hip/hip_bf16.h>
#include <math.h>

#define SEQ_LEN 1024
#define BATCH_N 8
#define DMODEL 256
#define DINNER 512
#define DSTATE 16
#define DTRANK 16
#define ROWS (BATCH_N * SEQ_LEN)   // 8192
#define NCHUNK 64
#define CHUNK (SEQ_LEN / NCHUNK)   // 16
#define BD 8                       // d-channels per block (scan)

typedef unsigned short u16;
typedef u16 u16x8 __attribute__((ext_vector_type(8)));
typedef short bf16x8 __attribute__((ext_vector_type(8)));
typedef float f32x4 __attribute__((ext_vector_type(4)));

__device__ __forceinline__ float siluf(float x) { return x / (1.f + expf(-x)); }
__device__ __forceinline__ float softplusf(float x) {
    return fmaxf(x, 0.f) + log1pf(expf(-fabsf(x)));
}
__device__ __forceinline__ u16 bf16_rne(float x) {
    unsigned u = __builtin_bit_cast(unsigned, x);
    return (u16)((u + 0x7FFFu + ((u >> 16) & 1u)) >> 16);
}
__device__ __forceinline__ void cvt_hl(float x, u16& h, u16& l) {
    unsigned u = __builtin_bit_cast(unsigned, x);
    unsigned hb = (u + 0x7FFFu + ((u >> 16) & 1u)) >> 16;
    h = (u16)hb;
    float hf = __builtin_bit_cast(float, hb << 16);
    l = bf16_rne(x - hf);
}
__device__ __forceinline__ float pair_f(u16 h, u16 l) {
    return __builtin_bit_cast(float, (unsigned)h << 16) +
           __builtin_bit_cast(float, (unsigned)l << 16);
}
// fragment-swizzled activation address: tensor [R rows][Kc cols] stored as
// [Kc/32][R][32]; elem (row,c) at ((c>>5)*R + row)*32 + (c&31)
__device__ __forceinline__ size_t swa(int R, int row, int c) {
    return ((size_t)(c >> 5) * R + row) * 32 + (c & 31);
}

// x fp32 [8192][64] -> swizzled bf16 hi/lo pairs
__global__ __launch_bounds__(256) void cvt_x_swz(
    const float* __restrict__ x, u16* __restrict__ dh, u16* __restrict__ dl)
{
    int i = blockIdx.x * 256 + threadIdx.x;   // < ROWS*64
    int row = i >> 6, c = i & 63;
    u16 h, l;
    cvt_hl(x[i], h, l);
    size_t sw = swa(ROWS, row, c);
    dh[sw] = h;
    dl[sw] = l;
}

// all 4 weight tensors -> fragment-swizzled single bf16 ([k/32][Npad][32])
// segments: Wp(256x64), W_in 4x(1024x256), W_x 4x(48->64 x 512), W_out 4x(256x512)
#define CWT (16384 + 4 * 262144 + 4 * 32768 + 4 * 131072)   // 1720320
__global__ __launch_bounds__(256) void cvt_w_swz(
    const float* __restrict__ Wp, const float* __restrict__ W_in,
    const float* __restrict__ W_x, const float* __restrict__ W_out,
    u16* __restrict__ Wpb, u16* __restrict__ Wib,
    u16* __restrict__ Wxb, u16* __restrict__ Wob)
{
    long i = (long)blockIdx.x * 256 + threadIdx.x;
    if (i >= CWT) return;
    if (i < 16384) {                       // Wp: N=256 K=64
        int n = (int)(i >> 6), k = (int)(i & 63);
        Wpb[((k >> 5) * 256 + n) * 32 + (k & 31)] = bf16_rne(Wp[n * 64 + k]);
        return;
    }
    i -= 16384;
    if (i < 4 * 262144) {                  // W_in: N=1024 K=256
        int l = (int)(i >> 18), r = (int)(i & 262143);
        int n = r >> 8, k = r & 255;
        Wib[l * 262144 + ((k >> 5) * 1024 + n) * 32 + (k & 31)] =
            bf16_rne(W_in[l * 262144 + n * 256 + k]);
        return;
    }
    i -= 4 * 262144;
    if (i < 4 * 32768) {                   // W_x: N=48 (pad 64) K=512
        int l = (int)(i >> 15), r = (int)(i & 32767);
        int n = r >> 9, k = r & 511;
        float v = (n < 48) ? W_x[l * 48 * 512 + n * 512 + k] : 0.f;
        Wxb[l * 32768 + ((k >> 5) * 64 + n) * 32 + (k & 31)] = bf16_rne(v);
        return;
    }
    i -= 4 * 32768;
    {                                      // W_out: N=256 K=512
        int l = (int)(i >> 17), r = (int)(i & 131071);
        int n = r >> 9, k = r & 511;
        Wob[l * 131072 + ((k >> 5) * 256 + n) * 32 + (k & 31)] =
            bf16_rne(W_out[l * 131072 + n * 512 + k]);
    }
}

// ---------------------------------------------------------------------------
// LDS-free MFMA GEMM on fragment-swizzled operands (round-11 measured-good).
// A = bf16 hi/lo pair (swizzled, R=M), B = single bf16 (swizzled, Npad rows).
// acc += Ah*B + Al*B. Block 64x64 = 4 waves 2x2; per wave-iter 6 coalesced
// u16x8 loads + 8 MFMAs. No barriers, no LDS.
// EPI 0: fp32 row-major C.  EPI 1: swizzled pair C.
// ---------------------------------------------------------------------------
template<int EPI>
__global__ __launch_bounds__(256) void gemm_sw(
    const u16* __restrict__ Ah, const u16* __restrict__ Al,
    const u16* __restrict__ B,
    const float* __restrict__ bias, float* __restrict__ C,
    u16* __restrict__ Ch, u16* __restrict__ Cl,
    int M, int N, int Npad, int K, int ldc)
{
    const int tid  = threadIdx.x;
    const int wave = tid >> 6, lane = tid & 63;
    const int bm   = blockIdx.y * 64, bn = blockIdx.x * 64;
    const int wm   = (wave >> 1) * 32, wn = (wave & 1) * 32;
    const int fr   = lane & 15, quad = lane >> 4;

    f32x4 acc[2][2];
#pragma unroll
    for (int i = 0; i < 2; i++)
#pragma unroll
        for (int j = 0; j < 2; j++) acc[i][j] = (f32x4){0.f, 0.f, 0.f, 0.f};

    const size_t a0 = (size_t)(bm + wm + fr) * 32 + quad * 8;
    const size_t a1 = a0 + 16 * 32;
    const size_t b0 = (size_t)(bn + wn + fr) * 32 + quad * 8;
    const size_t b1 = b0 + 16 * 32;
    const size_t astep = (size_t)M * 32;
    const size_t bstep = (size_t)Npad * 32;

    const u16* pah = Ah;
    const u16* pal = Al;
    const u16* pb  = B;
#pragma unroll 2
    for (int k0 = 0; k0 < K; k0 += 32) {
        bf16x8 ah0 = *(const bf16x8*)(pah + a0);
        bf16x8 ah1 = *(const bf16x8*)(pah + a1);
        bf16x8 al0 = *(const bf16x8*)(pal + a0);
        bf16x8 al1 = *(const bf16x8*)(pal + a1);
        bf16x8 bv0 = *(const bf16x8*)(pb + b0);
        bf16x8 bv1 = *(const bf16x8*)(pb + b1);
        acc[0][0] = __builtin_amdgcn_mfma_f32_16x16x32_bf16(ah0, bv0, acc[0][0], 0, 0, 0);
        acc[0][0] = __builtin_amdgcn_mfma_f32_16x16x32_bf16(al0, bv0, acc[0][0], 0, 0, 0);
        acc[0][1] = __builtin_amdgcn_mfma_f32_16x16x32_bf16(ah0, bv1, acc[0][1], 0, 0, 0);
        acc[0][1] = __builtin_amdgcn_mfma_f32_16x16x32_bf16(al0, bv1, acc[0][1], 0, 0, 0);
        acc[1][0] = __builtin_amdgcn_mfma_f32_16x16x32_bf16(ah1, bv0, acc[1][0], 0, 0, 0);
        acc[1][0] = __builtin_amdgcn_mfma_f32_16x16x32_bf16(al1, bv0, acc[1][0], 0, 0, 0);
        acc[1][1] = __builtin_amdgcn_mfma_f32_16x16x32_bf16(ah1, bv1, acc[1][1], 0, 0, 0);
        acc[1][1] = __builtin_amdgcn_mfma_f32_16x16x32_bf16(al1, bv1, acc[1][1], 0, 0, 0);
        pah += astep; pal += astep; pb += bstep;
    }

    // C/D layout (m89-verified): row = quad*4 + reg, col = fr within 16x16 frag
#pragma unroll
    for (int i = 0; i < 2; i++) {
        const int r0 = bm + wm + 16 * i + quad * 4;
#pragma unroll
        for (int reg = 0; reg < 4; reg++) {
            const int row = r0 + reg;
#pragma unroll
            for (int j = 0; j < 2; j++) {
                const int col = bn + wn + 16 * j + fr;
                if (col < N) {
                    float v = acc[i][j][reg];
                    if (bias) v += bias[col];
                    if (EPI == 0) {
                        C[(size_t)row * ldc + col] = v;
                    } else {
                        u16 h, l;
                        cvt_hl(v, h, l);
                        size_t sw = swa(M, row, col);
                        Ch[sw] = h;
                        Cl[sw] = l;
                    }
                }
            }
        }
    }
}

// ---------------------------------------------------------------------------
// Wide variant: 64x128 block (4 waves 2x2, each 32x64 = 2x4 frags).
// 16 MFMAs per 8 loads (2x the MFMA:load ratio) and half the A re-reads.
// fp32 row-major C only. N % 128 == 0 assumed (xz: N=1024).
// r18-measured best for the xz projection.
// ---------------------------------------------------------------------------
__global__ __launch_bounds__(256) void gemm_sw128(
    const u16* __restrict__ Ah, const u16* __restrict__ Al,
    const u16* __restrict__ B, float* __restrict__ C,
    int M, int Npad, int K, int ldc)
{
    const int tid  = threadIdx.x;
    const int wave = tid >> 6, lane = tid & 63;
    const int bm   = blockIdx.y * 64, bn = blockIdx.x * 128;
    const int wm   = (wave >> 1) * 32, wn = (wave & 1) * 64;
    const int fr   = lane & 15, quad = lane >> 4;

    f32x4 acc[2][4];
#pragma unroll
    for (int i = 0; i < 2; i++)
#pragma unroll
        for (int j = 0; j < 4; j++) acc[i][j] = (f32x4){0.f, 0.f, 0.f, 0.f};

    const size_t a0 = (size_t)(bm + wm + fr) * 32 + quad * 8;
    const size_t a1 = a0 + 16 * 32;
    size_t bofs[4];
#pragma unroll
    for (int j = 0; j < 4; j++)
        bofs[j] = (size_t)(bn + wn + 16 * j + fr) * 32 + quad * 8;
    const size_t astep = (size_t)M * 32;
    const size_t bstep = (size_t)Npad * 32;

    const u16* pah = Ah;
    const u16* pal = Al;
    const u16* pb  = B;
    for (int k0 = 0; k0 < K; k0 += 32) {
        bf16x8 ah0 = *(const bf16x8*)(pah + a0);
        bf16x8 ah1 = *(const bf16x8*)(pah + a1);
        bf16x8 al0 = *(const bf16x8*)(pal + a0);
        bf16x8 al1 = *(const bf16x8*)(pal + a1);
        bf16x8 bv[4];
#pragma unroll
        for (int j = 0; j < 4; j++) bv[j] = *(const bf16x8*)(pb + bofs[j]);
#pragma unroll
        for (int j = 0; j < 4; j++) {
            acc[0][j] = __builtin_amdgcn_mfma_f32_16x16x32_bf16(ah0, bv[j], acc[0][j], 0, 0, 0);
            acc[0][j] = __builtin_amdgcn_mfma_f32_16x16x32_bf16(al0, bv[j], acc[0][j], 0, 0, 0);
            acc[1][j] = __builtin_amdgcn_mfma_f32_16x16x32_bf16(ah1, bv[j], acc[1][j], 0, 0, 0);
            acc[1][j] = __builtin_amdgcn_mfma_f32_16x16x32_bf16(al1, bv[j], acc[1][j], 0, 0, 0);
        }
        pah += astep; pal += astep; pb += bstep;
    }

#pragma unroll
    for (int i = 0; i < 2; i++) {
        const int r0 = bm + wm + 16 * i + quad * 4;
#pragma unroll
        for (int reg = 0; reg < 4; reg++) {
            float* crow = C + (size_t)(r0 + reg) * ldc;
#pragma unroll
            for (int j = 0; j < 4; j++)
                crow[bn + wn + 16 * j + fr] = acc[i][j][reg];
        }
    }
}

// causal depthwise conv (k=4) + bias + silu -> swizzled bf16 pair xc.
// xz (fp32): [ROWS][1024], xh = cols 0..511
__global__ __launch_bounds__(256) void conv_silu_k(
    const float* __restrict__ xz, const float* __restrict__ cw,
    const float* __restrict__ cb, u16* __restrict__ xch, u16* __restrict__ xcl)
{
    int idx = blockIdx.x * 256 + threadIdx.x;
    int d = idx & (DINNER - 1);
    int row = idx >> 9;
    int t = row & (SEQ_LEN - 1);
    float4 w = *(const float4*)(cw + d * 4);
    float acc = cb[d];
    const float* p = xz + (size_t)row * 1024 + d;
    if (t >= 3) acc = fmaf(p[-3 * 1024], w.x, acc);
    if (t >= 2) acc = fmaf(p[-2 * 1024], w.y, acc);
    if (t >= 1) acc = fmaf(p[-1 * 1024], w.z, acc);
    acc = fmaf(p[0], w.w, acc);
    float v = siluf(acc);
    u16 h, l;
    cvt_hl(v, h, l);
    size_t sw = swa(ROWS, row, d);
    xch[sw] = h;
    xcl[sw] = l;
}

// dt v2: block = 512 threads (one per d), loops 16 rows; W_dt row held in
// registers, dtr row loads are wave-uniform (scalar-cache broadcast).
#define DT_RPB 16
__global__ __launch_bounds__(512) void dt_k(
    const float* __restrict__ xdbl,  // [ROWS][48]
    const float* __restrict__ Wdt,   // [512][16]
    const float* __restrict__ bdt,   // [512]
    float* __restrict__ dt)          // [ROWS][512]
{
    const int d  = threadIdx.x;          // 0..511
    const int r0 = blockIdx.x * DT_RPB;  // grid = ROWS/DT_RPB = 512
    float wv[16];
#pragma unroll
    for (int i = 0; i < 16; i += 4) *(float4*)&wv[i] = *(const float4*)(Wdt + d * 16 + i);
    const float bb = bdt[d];
#pragma unroll 4
    for (int r = 0; r < DT_RPB; ++r) {
        const float* q = xdbl + (size_t)(r0 + r) * 48;
        float qv[16];
#pragma unroll
        for (int i = 0; i < 16; i += 4) *(float4*)&qv[i] = *(const float4*)(q + i);
        float dot = bb;
#pragma unroll
        for (int i = 0; i < 16; i++) dot = fmaf(qv[i], wv[i], dot);
        dt[(size_t)(r0 + r) * 512 + d] = softplusf(dot);
    }
}

// ---------------------------------------------------------------------------
// Chunked selective scan (r14-exact: best measured 53.0 us, thrice-confirmed
// optimum). One thread per (b, d, chunk), 16 states in registers; dt
// precomputed; no A->C reg cache (spills — r8/r17). Round-7 swizzle
// (b = blk & 7 batch->XCD). y pair overwrites xc in place.
// ---------------------------------------------------------------------------
__global__ __launch_bounds__(512, 4) void scan_k(
    u16* __restrict__ xch,           // swizzled pair hi; in: xc, out: y
    u16* __restrict__ xcl,           // pair lo
    const float* __restrict__ dt,    // [ROWS][512] softplus'd
    const float* __restrict__ xdbl,  // [ROWS][48]  (B at +16, C at +32)
    const float* __restrict__ xz,    // [ROWS][1024]  z at +512
    const float* __restrict__ A_log, // [512][16]
    const float* __restrict__ Dp)    // [512]
{
    const int tid = threadIdx.x;
    const int dl  = tid & (BD - 1);      // 0..7
    const int ch  = tid >> 3;            // 0..63
    const int b   = blockIdx.x & 7;      // batch -> XCD partition
    const int dg  = blockIdx.x >> 3;     // 0..63
    const int d   = dg * BD + dl;

    __shared__ float ldsP[NCHUNK * BD * 16];   // 32 KB (reused as H0)
    __shared__ float ldsS[NCHUNK * BD * 16];   // 32 KB

    bool pow_ok = true;
#pragma unroll
    for (int n = 0; n < 16; n++) {
        float An = -expf(A_log[d * 16 + n]);
        pow_ok = pow_ok && (fabsf(An + (float)(n + 1)) <= 1e-3f * (float)(n + 1));
    }
    const int t0 = b * SEQ_LEN + ch * CHUNK;
    const int base = (ch * BD + dl) * 16;
    const size_t xcb = ((size_t)(d >> 5) * ROWS) * 32 + (d & 31);  // + row*32

    // ---- Phase A ----
    float S[16];
#pragma unroll
    for (int n = 0; n < 16; n++) S[n] = 0.f;
    float sdt = 0.f;
#pragma unroll 2
    for (int t = 0; t < CHUNK; ++t) {
        const size_t row = (size_t)(t0 + t);
        const float* xr = xdbl + row * 48;
        float Bv[16];
#pragma unroll
        for (int i = 0; i < 16; i += 4) *(float4*)&Bv[i] = *(const float4*)(xr + 16 + i);
        float xcv = pair_f(xch[xcb + row * 32], xcl[xcb + row * 32]);
        float dtv = dt[row * 512 + d];
        sdt += dtv;
        float u = dtv * xcv;
        float p[16];
        if (pow_ok) {
            float e1 = expf(-dtv);
            p[0] = e1;
#pragma unroll
            for (int n = 1; n < 8; n++) p[n] = p[n - 1] * e1;
            float e8 = p[7];
#pragma unroll
            for (int n = 8; n < 16; n++) p[n] = p[n - 8] * e8;
        } else {
#pragma unroll
            for (int n = 0; n < 16; n++)
                p[n] = exp2f(dtv * (-expf(A_log[d * 16 + n])) * 1.44269504f);
        }
#pragma unroll
        for (int n = 0; n < 16; n++) S[n] = fmaf(p[n], S[n], u * Bv[n]);
    }
    {
        float p[16];
        if (pow_ok) {
            float e1 = expf(-sdt);
            p[0] = e1;
#pragma unroll
            for (int n = 1; n < 8; n++) p[n] = p[n - 1] * e1;
            float e8 = p[7];
#pragma unroll
            for (int n = 8; n < 16; n++) p[n] = p[n - 8] * e8;
        } else {
#pragma unroll
            for (int n = 0; n < 16; n++)
                p[n] = exp2f(sdt * (-expf(A_log[d * 16 + n])) * 1.44269504f);
        }
#pragma unroll
        for (int i = 0; i < 16; i += 4) {
            *(float4*)&ldsP[base + i] = *(float4*)&p[i];
            *(float4*)&ldsS[base + i] = *(float4*)&S[i];
        }
    }
    __syncthreads();

    // ---- Phase B ----
    if (tid < BD * 16) {
        const int dd = tid >> 4;
        const int nn = tid & 15;
        float h = 0.f;
#pragma unroll 4
        for (int c = 0; c < NCHUNK; ++c) {
            const int idx = (c * BD + dd) * 16 + nn;
            float Pv = ldsP[idx];
            float Sv = ldsS[idx];
            ldsP[idx] = h;
            h = fmaf(Pv, h, Sv);
        }
    }
    __syncthreads();

    // ---- Phase C ----
    float h[16];
#pragma unroll
    for (int i = 0; i < 16; i += 4) *(float4*)&h[i] = *(float4*)&ldsP[base + i];
    const float Dd = Dp[d];
#pragma unroll 2
    for (int t = 0; t < CHUNK; ++t) {
        const size_t row = (size_t)(t0 + t);
        const float* xr = xdbl + row * 48;
        float Bv[16], Cv[16];
#pragma unroll
        for (int i = 0; i < 16; i += 4) *(float4*)&Bv[i] = *(const float4*)(xr + 16 + i);
#pragma unroll
        for (int i = 0; i < 16; i += 4) *(float4*)&Cv[i] = *(const float4*)(xr + 32 + i);
        float xcv = pair_f(xch[xcb + row * 32], xcl[xcb + row * 32]);
        float zv  = xz[row * 1024 + 512 + d];
        float dtv = dt[row * 512 + d];
        float u = dtv * xcv;
        float p[16];
        if (pow_ok) {
            float e1 = expf(-dtv);
            p[0] = e1;
#pragma unroll
            for (int n = 1; n < 8; n++) p[n] = p[n - 1] * e1;
            float e8 = p[7];
#pragma unroll
            for (int n = 8; n < 16; n++) p[n] = p[n - 8] * e8;
        } else {
#pragma unroll
            for (int n = 0; n < 16; n++)
                p[n] = exp2f(dtv * (-expf(A_log[d * 16 + n])) * 1.44269504f);
        }
        float y = 0.f;
#pragma unroll
        for (int n = 0; n < 16; n++) {
            h[n] = fmaf(p[n], h[n], u * Bv[n]);
            y = fmaf(h[n], Cv[n], y);
        }
        y = fmaf(Dd, xcv, y);
        y *= siluf(zv);
        u16 yh, yl;
        cvt_hl(y, yh, yl);
        xch[xcb + row * 32] = yh;
        xcl[xcb + row * 32] = yl;
    }
}

// LayerNorm over 256 features -> swizzled bf16 pair output; 4 rows per block.
__global__ __launch_bounds__(256) void ln_k(
    const float* __restrict__ X, const float* __restrict__ g,
    const float* __restrict__ b2, u16* __restrict__ Yh, u16* __restrict__ Yl)
{
    int lane = threadIdx.x & 63;
    int row = blockIdx.x * 4 + (threadIdx.x >> 6);
    const float4 v = *(const float4*)(X + (size_t)row * 256 + lane * 4);
    float s = v.x + v.y + v.z + v.w;
    float q = v.x * v.x + v.y * v.y + v.z * v.z + v.w * v.w;
#pragma unroll
    for (int o = 1; o < 64; o <<= 1) { s += __shfl_xor(s, o, 64); q += __shfl_xor(q, o, 64); }
    float mean = s * (1.f / 256.f);
    float var = q * (1.f / 256.f) - mean * mean;
    float inv = rsqrtf(var + 1e-5f);
    float4 gg = *(const float4*)(g + lane * 4);
    float4 bb = *(const float4*)(b2 + lane * 4);
    float o0 = (v.x - mean) * inv * gg.x + bb.x;
    float o1 = (v.y - mean) * inv * gg.y + bb.y;
    float o2 = (v.z - mean) * inv * gg.z + bb.z;
    float o3 = (v.w - mean) * inv * gg.w + bb.w;
    ushort4 h4, l4;
    cvt_hl(o0, h4.x, l4.x); cvt_hl(o1, h4.y, l4.y);
    cvt_hl(o2, h4.z, l4.z); cvt_hl(o3, h4.w, l4.w);
    size_t sw = swa(ROWS, row, lane * 4);
    *(ushort4*)(Yh + sw) = h4;
    *(ushort4*)(Yl + sw) = l4;
}

// final stage 1: per (b, t-chunk of 16) partial dot with Wf -> part[512]
__global__ __launch_bounds__(256) void final1_k(
    const u16* __restrict__ Hh, const u16* __restrict__ Hl,
    const float* __restrict__ Wf, float* __restrict__ part)
{
    const int b   = blockIdx.x >> 6;     // 0..7
    const int ckt = blockIdx.x & 63;     // 0..63
    const int c   = threadIdx.x;
    const size_t cb = ((size_t)(c >> 5) * ROWS) * 32 + (c & 31);
    const int tbase = b * SEQ_LEN + ckt * 16;
    float s = 0.f;
#pragma unroll 4
    for (int t = 0; t < 16; t++) {
        size_t sw = cb + (size_t)(tbase + t) * 32;
        s += pair_f(Hh[sw], Hl[sw]);
    }
    float v = s * Wf[c];
    int lane = c & 63;
#pragma unroll
    for (int o = 1; o < 64; o <<= 1) v += __shfl_xor(v, o, 64);
    __shared__ float red[4];
    if (lane == 0) red[c >> 6] = v;
    __syncthreads();
    if (c == 0) part[blockIdx.x] = red[0] + red[1] + red[2] + red[3];
}

// final stage 2: combine 64 partials per batch
__global__ __launch_bounds__(512) void final2_k(
    const float* __restrict__ part, const float* __restrict__ bf,
    float* __restrict__ out)
{
    int tid = threadIdx.x;            // 512
    int b = tid >> 6, i = tid & 63;
    float v = part[b * 64 + i];
#pragma unroll
    for (int o = 1; o < 64; o <<= 1) v += __shfl_xor(v, o, 64);
    if (i == 0) out[b] = v * (1.f / 1024.f) + bf[0];
}

extern "C" void kernel_launch(void* const* d_in, const int* in_sizes, int n_in,
                              void* d_out, int out_size, void* d_ws, size_t ws_size,
                              hipStream_t stream)
{
    const float* x      = (const float*)d_in[0];
    const float* Wp     = (const float*)d_in[1];
    const float* bp     = (const float*)d_in[2];
    const float* W_in   = (const float*)d_in[3];
    const float* conv_w = (const float*)d_in[4];
    const float* conv_b = (const float*)d_in[5];
    const float* W_x    = (const float*)d_in[6];
    const float* W_dt   = (const float*)d_in[7];
    const float* b_dt   = (const float*)d_in[8];
    const float* A_log  = (const float*)d_in[9];
    const float* Dp     = (const float*)d_in[10];
    const float* W_out  = (const float*)d_in[11];
    const float* ln_g   = (const float*)d_in[12];
    const float* ln_b   = (const float*)d_in[13];
    const float* Wf     = (const float*)d_in[14];
    const float* bf     = (const float*)d_in[15];

    // ---- workspace layout ----
    char* w = (char*)d_ws;
    float* bufXZ = (float*)w;            w += (size_t)ROWS * 1024 * 4;  // 33.55 MB
    float* bufDT = (float*)w;            w += (size_t)ROWS * 512 * 4;   // 16.78 MB
    float* bufXD = (float*)w;            w += (size_t)ROWS * 48 * 4;    // 1.57 MB
    u16* xch  = (u16*)w;                 w += (size_t)ROWS * 512 * 2;
    u16* xcl  = (u16*)w;                 w += (size_t)ROWS * 512 * 2;
    u16* hh   = (u16*)w;                 w += (size_t)ROWS * 256 * 2;
    u16* hl   = (u16*)w;                 w += (size_t)ROWS * 256 * 2;
    u16* xih  = (u16*)w;                 w += (size_t)ROWS * 64 * 2;
    u16* xil  = (u16*)w;                 w += (size_t)ROWS * 64 * 2;
    u16* Wpb  = (u16*)w;                 w += (size_t)256 * 64 * 2;
    u16* Wib  = (u16*)w;                 w += (size_t)4 * 1024 * 256 * 2;
    u16* Wxb  = (u16*)w;                 w += (size_t)4 * 64 * 512 * 2;   // padded
    u16* Wob  = (u16*)w;                 w += (size_t)4 * 256 * 512 * 2;
    float* part = (float*)w;             w += 512 * 4;
    float* bufO = bufXZ;   // [ROWS][256] overlays bufXZ (dead after scan)

    dim3 blk(256);

    // one-time conversions (swizzled)
    cvt_x_swz<<<dim3(ROWS * 64 / 256), blk, 0, stream>>>(x, xih, xil);
    cvt_w_swz<<<dim3((CWT + 255) / 256), blk, 0, stream>>>(
        Wp, W_in, W_x, W_out, Wpb, Wib, Wxb, Wob);

    // h = x @ Wp^T + bp  (M=8192, N=Npad=256, K=64) -> swizzled pair
    gemm_sw<1><<<dim3(4, 128), blk, 0, stream>>>(xih, xil, Wpb, bp,
                                                 nullptr, hh, hl,
                                                 ROWS, DMODEL, DMODEL, 64, 0);

    for (int l = 0; l < 4; ++l) {
        const u16* Wil = Wib + (size_t)l * 1024 * 256;
        const u16* Wxl = Wxb + (size_t)l * 64 * 512;
        const u16* Wol = Wob + (size_t)l * 256 * 512;
        const float* cw  = conv_w + (size_t)l * DINNER * 4;
        const float* cb  = conv_b + (size_t)l * DINNER;
        const float* Wdt = W_dt   + (size_t)l * DINNER * DTRANK;
        const float* bdt = b_dt   + (size_t)l * DINNER;
        const float* Al  = A_log  + (size_t)l * DINNER * DSTATE;
        const float* Dl  = Dp     + (size_t)l * DINNER;
        const float* lg  = ln_g   + (size_t)l * DMODEL;
        const float* lb  = ln_b   + (size_t)l * DMODEL;

        // xz = h @ W_in^T  (N=Npad=1024, K=256) -> fp32, wide 64x128 tiles
        gemm_sw128<<<dim3(8, 128), blk, 0, stream>>>(hh, hl, Wil, bufXZ,
                                                     ROWS, 1024, DMODEL, 1024);
        // conv + silu -> xc swizzled pairs
        conv_silu_k<<<dim3(ROWS * DINNER / 256), blk, 0, stream>>>(bufXZ, cw, cb, xch, xcl);
        // x_dbl = xc @ W_x^T  (N=48, Npad=64, K=512) -> fp32 row-major
        gemm_sw<0><<<dim3(1, 128), blk, 0, stream>>>(xch, xcl, Wxl, nullptr,
                                                     bufXD, nullptr, nullptr,
                                                     ROWS, 48, 64, DINNER, 48);
        // dt = softplus(dtr @ W_dt^T + b_dt)  (rank-16, register-resident W_dt)
        dt_k<<<dim3(ROWS / DT_RPB), dim3(512), 0, stream>>>(bufXD, Wdt, bdt, bufDT);
        // chunked selective scan (r14-exact) -> y pairs overwrite xc
        scan_k<<<dim3(512), dim3(512), 0, stream>>>(xch, xcl, bufDT, bufXD, bufXZ, Al, Dl);
        // out = y @ W_out^T  (N=Npad=256, K=512) -> fp32 bufO
        gemm_sw<0><<<dim3(4, 128), blk, 0, stream>>>(xch, xcl, Wol, nullptr,
                                                     bufO, nullptr, nullptr,
                                                     ROWS, DMODEL, DMODEL, DINNER, DMODEL);
        // layernorm -> h swizzled pairs
        ln_k<<<dim3(ROWS / 4), blk, 0, stream>>>(bufO, lg, lb, hh, hl);
    }

    final1_k<<<dim3(512), blk, 0, stream>>>(hh, hl, Wf, part);
    final2_k<<<dim3(1), dim3(512), 0, stream>>>(part, bf, (float*)d_out);

    (void)in_sizes; (void)n_in; (void)out_size; (void)ws_size;
}